// Round 6
// baseline (150.149 us; speedup 1.0000x reference)
//
#include <hip/hip_runtime.h>
#include <hip/hip_bf16.h>

// MMD loss via bf16 MFMA Gram matrix — BARRIER-FREE direct-load GEMM.
// z = [xf; yf] (8192 x 256). result = (1/4096^2) * (8192*NSIG + sum_{i<j} 2 s_i s_j K_ij)
// Gram-matrix trick: A-frag and B-frag of mfma_16x16x32_bf16 are both 16B
// contiguous row chunks of Z -> load fragments straight from global (L2-resident),
// no LDS, no __syncthreads in the K-loop. 8256 independent 64x64 wave-tiles.
//
// R4 lesson: no per-block __threadfence in hot kernel. R5 lesson: never force
// occupancy past the register budget (launch_bounds(256,5) => spill => 157MB scratch).
// ws: [0,4MiB) bf16 Z[8192][256]; float norms[8192]; double acc.

#define NSIG 5
#define NT64 128                        // 8192/64 tiles per side
#define NWT  ((NT64 * (NT64 + 1)) / 2)  // 8256 wave-tiles
#define NBLK (NWT / 4)                  // 2064 blocks x 4 waves (exact)

typedef __attribute__((ext_vector_type(8))) short short8;
typedef __attribute__((ext_vector_type(4))) float floatx4;

// ---- prep: (B,C,H,W) fp32 -> Z[n][c] bf16 row-major + norms, via LDS transpose ----
__global__ __launch_bounds__(256) void prep_kernel(const float* __restrict__ x,
                                                   const float* __restrict__ y,
                                                   ushort* __restrict__ Z,
                                                   float* __restrict__ norms,
                                                   double* __restrict__ acc) {
    const int bid = blockIdx.x;           // s(1) | b(2) | strip(6)
    const int t = threadIdx.x;
    if (bid == 0 && t == 0) *acc = 0.0;
    const int s = bid >> 8;
    const int b = (bid >> 6) & 3;
    const int p0 = (bid & 63) << 4;
    const float* src = s ? y : x;
    const int n0 = (s << 12) + (b << 10) + p0;

    __shared__ float tile[256][17];

    const int cg = t >> 2;
    const int p4 = (t & 3) << 2;
#pragma unroll
    for (int pass = 0; pass < 4; ++pass) {
        const int c = cg + (pass << 6);
        const float4 v = *(const float4*)(src + (((size_t)((b << 8) + c)) << 10) + p0 + p4);
        tile[c][p4] = v.x; tile[c][p4 + 1] = v.y; tile[c][p4 + 2] = v.z; tile[c][p4 + 3] = v.w;
    }
    __syncthreads();

    const int r = t >> 4;
    const int q = t & 15;
    float nsum = 0.f;
#pragma unroll
    for (int h = 0; h < 2; ++h) {
        const int c0 = (q + (h << 4)) << 3;
        uint pk[4];
#pragma unroll
        for (int j = 0; j < 4; ++j) {
            const float f0 = tile[c0 + 2 * j][r];
            const float f1 = tile[c0 + 2 * j + 1][r];
            const __hip_bfloat16 h0 = __float2bfloat16(f0);
            const __hip_bfloat16 h1 = __float2bfloat16(f1);
            const float q0 = __bfloat162float(h0), q1 = __bfloat162float(h1);
            nsum = fmaf(q0, q0, nsum);
            nsum = fmaf(q1, q1, nsum);
            pk[j] = (uint)(*(const ushort*)&h0) | ((uint)(*(const ushort*)&h1) << 16);
        }
        *(uint4*)(Z + (size_t)(n0 + r) * 256 + c0) = make_uint4(pk[0], pk[1], pk[2], pk[3]);
    }
#pragma unroll
    for (int off = 1; off < 16; off <<= 1) nsum += __shfl_xor(nsum, off, 64);
    if (q == 0) norms[n0 + r] = nsum;
}

// ---- barrier-free GEMM + skip-list epilogue. One 64x64 tile per wave. ----
__global__ __launch_bounds__(256, 3) void gemm_epi(const ushort* __restrict__ Z,
                                                   const float* __restrict__ norms,
                                                   const float* __restrict__ sigmas,
                                                   double* __restrict__ acc) {
    __shared__ float wsum[4];

    const int t = threadIdx.x;
    const int w = t >> 6, l = t & 63;
    const int L = (blockIdx.x << 2) + w;          // wave-tile id, 0..8255

    // decode triangular (ti <= tj), NT64=128: TRI(b) = b*(257-b)/2
#define TRI64(b) (((b) * (257 - (b))) / 2)
    int ti = (int)((257.0f - sqrtf(66049.0f - 8.0f * (float)L)) * 0.5f);
    ti = ti < 0 ? 0 : (ti > NT64 - 1 ? NT64 - 1 : ti);
    while (TRI64(ti + 1) <= L) ++ti;
    while (TRI64(ti) > L) --ti;
    const int tj = ti + (L - TRI64(ti));

    const int i0 = ti << 6, j0 = tj << 6;
    const int m = l & 15, q = l >> 4;

    // per-lane element offsets (ushort units); chunk ck adds ck*32 (imm-foldable 64B)
    int offA[4], offB[4];
#pragma unroll
    for (int f = 0; f < 4; ++f) {
        offA[f] = ((i0 + (f << 4) + m) << 8) + (q << 3);
        offB[f] = ((j0 + (f << 4) + m) << 8) + (q << 3);
    }

    floatx4 accf[4][4];
#pragma unroll
    for (int fi = 0; fi < 4; ++fi)
#pragma unroll
        for (int fj = 0; fj < 4; ++fj) accf[fi][fj] = (floatx4){0.f, 0.f, 0.f, 0.f};

    short8 curA[4], curB[4], nxtA[4], nxtB[4];
#pragma unroll
    for (int f = 0; f < 4; ++f) {
        curA[f] = *(const short8*)(Z + offA[f]);
        curB[f] = *(const short8*)(Z + offB[f]);
    }

#pragma unroll
    for (int ck = 0; ck < 8; ++ck) {
        if (ck < 7) {
            const int ko = (ck + 1) << 5;
#pragma unroll
            for (int f = 0; f < 4; ++f) {
                nxtA[f] = *(const short8*)(Z + offA[f] + ko);
                nxtB[f] = *(const short8*)(Z + offB[f] + ko);
            }
        }
#pragma unroll
        for (int fi = 0; fi < 4; ++fi)
#pragma unroll
            for (int fj = 0; fj < 4; ++fj)
                accf[fi][fj] = __builtin_amdgcn_mfma_f32_16x16x32_bf16(curA[fi], curB[fj], accf[fi][fj], 0, 0, 0);
        if (ck < 7) {
#pragma unroll
            for (int f = 0; f < 4; ++f) { curA[f] = nxtA[f]; curB[f] = nxtB[f]; }
        }
    }

    // ---- epilogue ----
    float c2[NSIG];
#pragma unroll
    for (int k = 0; k < NSIG; ++k) c2[k] = (-0.5f / sigmas[k]) * 1.44269504f;  // -beta*log2(e)

    const bool diag = (ti == tj);
    const float sgn2 = ((ti < 64) == (tj < 64)) ? 2.f : -2.f;

#pragma unroll
    for (int fi = 0; fi < 4; ++fi) {
        const floatx4 ni4 = *(const floatx4*)(norms + i0 + (fi << 4) + (q << 2));
#pragma unroll
        for (int fj = 0; fj < 4; ++fj) {
            const float njs = norms[j0 + (fj << 4) + m];
#pragma unroll
            for (int v = 0; v < 4; ++v) {
                float d = fmaf(-2.f, accf[fi][fj][v], ni4[v] + njs);
                d = fmaxf(d, 0.f);
                if (diag) {
                    const int dif = ((fi - fj) << 4) + ((q << 2) + v) - m;   // gi - gj
                    d = (dif < 0) ? d : 3.0e9f;    // keep strictly-upper pairs only
                }
                accf[fi][fj][v] = d;
            }
        }
    }

    float dmin = accf[0][0][0];
#pragma unroll
    for (int fi = 0; fi < 4; ++fi)
#pragma unroll
        for (int fj = 0; fj < 4; ++fj)
#pragma unroll
            for (int v = 0; v < 4; ++v) dmin = fminf(dmin, accf[fi][fj][v]);
#pragma unroll
    for (int off = 1; off < 64; off <<= 1) dmin = fminf(dmin, __shfl_xor(dmin, off, 64));

    float lsum = 0.f;
#pragma unroll
    for (int k = 0; k < NSIG; ++k) {
        if (c2[k] * dmin >= -126.f) {     // wave-uniform: skip iff every exp underflows (exact in fp32)
#pragma unroll
            for (int fi = 0; fi < 4; ++fi)
#pragma unroll
                for (int fj = 0; fj < 4; ++fj)
#pragma unroll
                    for (int v = 0; v < 4; ++v)
                        lsum += __builtin_amdgcn_exp2f(c2[k] * accf[fi][fj][v]);
        }
    }
    lsum *= sgn2;

#pragma unroll
    for (int off = 32; off > 0; off >>= 1) lsum += __shfl_down(lsum, off, 64);
    if (l == 0) wsum[w] = lsum;
    __syncthreads();
    if (t == 0) atomicAdd(acc, (double)(wsum[0] + wsum[1] + wsum[2] + wsum[3]));
}

__global__ void finalize_kernel(const double* __restrict__ acc, float* __restrict__ out) {
    out[0] = (float)((*acc + 8192.0 * NSIG) * (1.0 / (4096.0 * 4096.0)));
}

extern "C" void kernel_launch(void* const* d_in, const int* in_sizes, int n_in,
                              void* d_out, int out_size, void* d_ws, size_t ws_size,
                              hipStream_t stream) {
    const float* x   = (const float*)d_in[0];
    const float* y   = (const float*)d_in[1];
    const float* sig = (const float*)d_in[2];

    ushort* Z    = (ushort*)d_ws;                                   // 4 MiB
    float* norms = (float*)((char*)d_ws + (size_t)8192 * 256 * 2);  // 32 KiB
    double* acc  = (double*)((char*)norms + 8192 * sizeof(float));
    float* out   = (float*)d_out;

    prep_kernel<<<512, 256, 0, stream>>>(x, y, Z, norms, acc);
    gemm_epi<<<NBLK, 256, 0, stream>>>(Z, norms, sig, acc);
    finalize_kernel<<<1, 1, 0, stream>>>(acc, out);
}

// Round 7
// 110.794 us; speedup vs baseline: 1.3552x; 1.3552x over previous
//
#include <hip/hip_runtime.h>
#include <hip/hip_bf16.h>

// MMD loss via bf16 MFMA Gram matrix.
// z = [xf; yf] (8192 x 256). result = (1/4096^2) * (8192*NSIG + sum_{i<j} 2 s_i s_j K_ij)
//
// R6 lesson: scattered vector-memory ops (16 rows x 512B stride per wave inst)
// serialize in the TA (~16-64 cyc/inst). Fix: CHUNKED-SWIZZLED Z layout so GEMM
// staging is contiguous: Zc[ck][row][32k], 64B/row/chunk, bank-swizzle baked in
// (stored quad = q ^ ((row>>1)&3)). Staging a 128-row tile chunk = one linear
// 8KB block; each wave: 2 glds16 with lane l at base + l*16 (perfect coalescing).
// R4 lesson: no per-block __threadfence in hot kernel. R5 lesson: never force
// occupancy past the register budget (spill => scratch traffic).
//
// ws: [0,4MiB) bf16 Zc; float norms[8192]; double acc.

#define NSIG 5
#define NT   64
#define NBLK ((NT * (NT + 1)) / 2)   // 2080
#define CKS  262144                   // chunk stride in ushorts: 8192 rows * 32

typedef __attribute__((ext_vector_type(8))) short short8;
typedef __attribute__((ext_vector_type(4))) float floatx4;

__device__ __forceinline__ void glds16(const ushort* g, ushort* l) {
    __builtin_amdgcn_global_load_lds((const __attribute__((address_space(1))) void*)g,
                                     (__attribute__((address_space(3))) void*)l,
                                     16, 0, 0);
}

// ---- prep: (B,C,H,W) fp32 -> Zc chunked-swizzled bf16 + norms ----
// 512 blocks, each one (s, b, 16-row p-strip): [256 c][16 p] fp32 tile via LDS.
__global__ __launch_bounds__(256) void prep_kernel(const float* __restrict__ x,
                                                   const float* __restrict__ y,
                                                   ushort* __restrict__ Zc,
                                                   float* __restrict__ norms,
                                                   double* __restrict__ acc) {
    const int bid = blockIdx.x;           // s(1) | b(2) | strip(6)
    const int t = threadIdx.x;
    if (bid == 0 && t == 0) *acc = 0.0;
    const int s = bid >> 8;
    const int b = (bid >> 6) & 3;
    const int p0 = (bid & 63) << 4;
    const float* src = s ? y : x;
    const int n0 = (s << 12) + (b << 10) + p0;

    __shared__ float tile[256][17];

    const int cg = t >> 2;
    const int p4 = (t & 3) << 2;
#pragma unroll
    for (int pass = 0; pass < 4; ++pass) {
        const int c = cg + (pass << 6);
        const float4 v = *(const float4*)(src + (((size_t)((b << 8) + c)) << 10) + p0 + p4);
        tile[c][p4] = v.x; tile[c][p4 + 1] = v.y; tile[c][p4 + 2] = v.z; tile[c][p4 + 3] = v.w;
    }
    __syncthreads();

    const int r = t >> 4;                 // row within strip
    const int q = t & 15;
    const int row = n0 + r;
    const int sw = (row >> 1) & 3;        // bank swizzle baked into global layout
    float nsum = 0.f;
#pragma unroll
    for (int h = 0; h < 2; ++h) {
        const int j = q + (h << 4);       // logical 8-elem group 0..31
        const int ck = j >> 2;            // K-chunk 0..7
        const int sq = (j & 3) ^ sw;      // stored quad within chunk
        const int c0 = j << 3;            // first c of this group
        uint pk[4];
#pragma unroll
        for (int jj = 0; jj < 4; ++jj) {
            const float f0 = tile[c0 + 2 * jj][r];
            const float f1 = tile[c0 + 2 * jj + 1][r];
            const __hip_bfloat16 h0 = __float2bfloat16(f0);
            const __hip_bfloat16 h1 = __float2bfloat16(f1);
            const float q0 = __bfloat162float(h0), q1 = __bfloat162float(h1);
            nsum = fmaf(q0, q0, nsum);
            nsum = fmaf(q1, q1, nsum);
            pk[jj] = (uint)(*(const ushort*)&h0) | ((uint)(*(const ushort*)&h1) << 16);
        }
        *(uint4*)(Zc + (size_t)ck * CKS + (size_t)row * 32 + (sq << 3)) =
            make_uint4(pk[0], pk[1], pk[2], pk[3]);
    }
#pragma unroll
    for (int off = 1; off < 16; off <<= 1) nsum += __shfl_xor(nsum, off, 64);
    if (q == 0) norms[row] = nsum;
}

// ---- GEMM (bf16 MFMA, dbuf, coalesced glds staging) + skip-list epilogue ----
__global__ __launch_bounds__(256) void gemm_epi(const ushort* __restrict__ Zc,
                                                const float* __restrict__ norms,
                                                const float* __restrict__ sigmas,
                                                double* __restrict__ acc) {
    __shared__ ushort lA[2][4096];   // [buf][128 rows x 32 k], swizzled, 8KB each
    __shared__ ushort lB[2][4096];
    __shared__ float wsum[4];

    const int L = blockIdx.x;
#define TRI(b) ((b) * NT - ((b) * ((b) - 1)) / 2)
    int bi = (int)((129.0f - sqrtf((float)(129 * 129 - 8 * L))) * 0.5f);
    if (bi < 0) bi = 0;
    if (bi > NT - 1) bi = NT - 1;
    while (TRI(bi + 1) <= L) ++bi;
    while (TRI(bi) > L) --bi;
    const int bj = bi + (L - TRI(bi));

    const int i0 = bi << 7, j0 = bj << 7;
    const int t = threadIdx.x;
    const int w = t >> 6, l = t & 63;
    const int wi = w >> 1, wj = w & 1;

    // staging: wave w stages tile rows [w*32, w*32+32) = 2KB contiguous per side.
    // lane l -> 16B at base + l*16 (perfectly coalesced); LDS dest lane-linear.
    const ushort* gA = Zc + (size_t)(i0 + (w << 5)) * 32 + (l << 3);
    const ushort* gB = Zc + (size_t)(j0 + (w << 5)) * 32 + (l << 3);
    const int ldo = w << 10;              // wave's LDS base (ushorts): w*32 rows * 32

    // fragment LDS offsets: row-local ra, logical quad q -> stored quad q^((ra>>1)&3)
    const int lane_m = l & 15, lane_q = l >> 4;
    int aoff[4], boff[4];
#pragma unroll
    for (int f = 0; f < 4; ++f) {
        const int ra = (wi << 6) + (f << 4) + lane_m;
        aoff[f] = (ra << 5) + ((lane_q ^ ((ra >> 1) & 3)) << 3);
        const int rb = (wj << 6) + (f << 4) + lane_m;
        boff[f] = (rb << 5) + ((lane_q ^ ((rb >> 1) & 3)) << 3);
    }

    floatx4 accf[4][4];
#pragma unroll
    for (int fi = 0; fi < 4; ++fi)
#pragma unroll
        for (int fj = 0; fj < 4; ++fj) accf[fi][fj] = (floatx4){0.f, 0.f, 0.f, 0.f};

    // prefetch chunk 0 -> buf 0
    glds16(gA, &lA[0][ldo]); glds16(gA + 512, &lA[0][ldo + 512]);
    glds16(gB, &lB[0][ldo]); glds16(gB + 512, &lB[0][ldo + 512]);

    for (int ck = 0; ck < 8; ++ck) {
        const int cur = ck & 1;
        __syncthreads();                   // buf[cur] staged; buf[cur^1] reads done
        if (ck < 7) {
            const int nxt = cur ^ 1;
            const size_t ko = (size_t)(ck + 1) * CKS;
            glds16(gA + ko, &lA[nxt][ldo]); glds16(gA + ko + 512, &lA[nxt][ldo + 512]);
            glds16(gB + ko, &lB[nxt][ldo]); glds16(gB + ko + 512, &lB[nxt][ldo + 512]);
        }
        short8 af[4], bfr[4];
#pragma unroll
        for (int f = 0; f < 4; ++f) {
            af[f]  = *(const short8*)(&lA[cur][aoff[f]]);
            bfr[f] = *(const short8*)(&lB[cur][boff[f]]);
        }
#pragma unroll
        for (int fi = 0; fi < 4; ++fi)
#pragma unroll
            for (int fj = 0; fj < 4; ++fj)
                accf[fi][fj] = __builtin_amdgcn_mfma_f32_16x16x32_bf16(af[fi], bfr[fj], accf[fi][fj], 0, 0, 0);
    }

    // ---- epilogue ----
    float c2[NSIG];
#pragma unroll
    for (int k = 0; k < NSIG; ++k) c2[k] = (-0.5f / sigmas[k]) * 1.44269504f;  // -beta*log2(e)

    const float* nA = norms + i0 + (wi << 6);
    const float* nB = norms + j0 + (wj << 6);
    const bool diag = (bi == bj);
    const float sgn2 = ((bi < 32) == (bj < 32)) ? 2.f : -2.f;

#pragma unroll
    for (int fi = 0; fi < 4; ++fi) {
        const floatx4 ni4 = *(const floatx4*)(nA + (fi << 4) + (lane_q << 2));
#pragma unroll
        for (int fj = 0; fj < 4; ++fj) {
            const float njs = nB[(fj << 4) + lane_m];
#pragma unroll
            for (int v = 0; v < 4; ++v) {
                float d = fmaf(-2.f, accf[fi][fj][v], ni4[v] + njs);
                d = fmaxf(d, 0.f);
                if (diag) {
                    const int dif = ((wi - wj) << 6) + ((fi - fj) << 4) + ((lane_q << 2) + v) - lane_m;
                    d = (dif < 0) ? d : 3.0e9f;   // keep strictly-upper pairs only
                }
                accf[fi][fj][v] = d;
            }
        }
    }

    float dmin = accf[0][0][0];
#pragma unroll
    for (int fi = 0; fi < 4; ++fi)
#pragma unroll
        for (int fj = 0; fj < 4; ++fj)
#pragma unroll
            for (int v = 0; v < 4; ++v) dmin = fminf(dmin, accf[fi][fj][v]);
#pragma unroll
    for (int off = 1; off < 64; off <<= 1) dmin = fminf(dmin, __shfl_xor(dmin, off, 64));

    float lsum = 0.f;
#pragma unroll
    for (int k = 0; k < NSIG; ++k) {
        if (c2[k] * dmin >= -126.f) {     // wave-uniform: skip iff every exp underflows (exact in fp32)
#pragma unroll
            for (int fi = 0; fi < 4; ++fi)
#pragma unroll
                for (int fj = 0; fj < 4; ++fj)
#pragma unroll
                    for (int v = 0; v < 4; ++v)
                        lsum += __builtin_amdgcn_exp2f(c2[k] * accf[fi][fj][v]);
        }
    }
    lsum *= sgn2;

#pragma unroll
    for (int off = 32; off > 0; off >>= 1) lsum += __shfl_down(lsum, off, 64);
    if (l == 0) wsum[w] = lsum;
    __syncthreads();
    if (t == 0) atomicAdd(acc, (double)(wsum[0] + wsum[1] + wsum[2] + wsum[3]));
}

__global__ void finalize_kernel(const double* __restrict__ acc, float* __restrict__ out) {
    out[0] = (float)((*acc + 8192.0 * NSIG) * (1.0 / (4096.0 * 4096.0)));
}

extern "C" void kernel_launch(void* const* d_in, const int* in_sizes, int n_in,
                              void* d_out, int out_size, void* d_ws, size_t ws_size,
                              hipStream_t stream) {
    const float* x   = (const float*)d_in[0];
    const float* y   = (const float*)d_in[1];
    const float* sig = (const float*)d_in[2];

    ushort* Zc   = (ushort*)d_ws;                                   // 4 MiB
    float* norms = (float*)((char*)d_ws + (size_t)8192 * 256 * 2);  // 32 KiB
    double* acc  = (double*)((char*)norms + 8192 * sizeof(float));
    float* out   = (float*)d_out;

    prep_kernel<<<512, 256, 0, stream>>>(x, y, Zc, norms, acc);
    gemm_epi<<<NBLK, 256, 0, stream>>>(Zc, norms, sig, acc);
    finalize_kernel<<<1, 1, 0, stream>>>(acc, out);
}

// Round 8
// 110.015 us; speedup vs baseline: 1.3648x; 1.0071x over previous
//
#include <hip/hip_runtime.h>
#include <hip/hip_bf16.h>

// MMD loss via bf16 MFMA Gram matrix — barrier-free, LDS-free GEMM with
// perfectly-coalesced direct-to-register fragment loads from the chunked-
// swizzled Zc layout (R7): Zc[ck][row][32], stored quad = q ^ ((row>>1)&3).
// For a 64x64 wave-tile, each mfma fragment (16 rows x 4 quads) is a bijection
// onto one contiguous 1KB block of Zc -> one global_load_dwordx4 per frag,
// no scatter (R6 lesson), no barriers in the K-loop (R3/R7 plateau lesson).
//
// R4 lesson: no per-block __threadfence in hot kernel.
// R5 lesson: never force occupancy past the register budget (spill).
//
// z = [xf; yf] (8192 x 256). result = (1/4096^2) * (8192*NSIG + sum_{i<j} 2 s_i s_j K_ij)
// ws: [0,4MiB) bf16 Zc; float norms[8192]; double acc.

#define NSIG 5
#define CKS  262144                     // chunk stride in ushorts: 8192 rows * 32
#define NT64 128                        // 8192/64 wave-tiles per side
#define NWT  ((NT64 * (NT64 + 1)) / 2)  // 8256
#define NBLK (NWT / 4)                  // 2064 blocks x 4 waves

typedef __attribute__((ext_vector_type(8))) short short8;
typedef __attribute__((ext_vector_type(4))) float floatx4;

// ---- prep: (B,C,H,W) fp32 -> Zc chunked-swizzled bf16 + norms (unchanged from R7) ----
__global__ __launch_bounds__(256) void prep_kernel(const float* __restrict__ x,
                                                   const float* __restrict__ y,
                                                   ushort* __restrict__ Zc,
                                                   float* __restrict__ norms,
                                                   double* __restrict__ acc) {
    const int bid = blockIdx.x;           // s(1) | b(2) | strip(6)
    const int t = threadIdx.x;
    if (bid == 0 && t == 0) *acc = 0.0;
    const int s = bid >> 8;
    const int b = (bid >> 6) & 3;
    const int p0 = (bid & 63) << 4;
    const float* src = s ? y : x;
    const int n0 = (s << 12) + (b << 10) + p0;

    __shared__ float tile[256][17];

    const int cg = t >> 2;
    const int p4 = (t & 3) << 2;
#pragma unroll
    for (int pass = 0; pass < 4; ++pass) {
        const int c = cg + (pass << 6);
        const float4 v = *(const float4*)(src + (((size_t)((b << 8) + c)) << 10) + p0 + p4);
        tile[c][p4] = v.x; tile[c][p4 + 1] = v.y; tile[c][p4 + 2] = v.z; tile[c][p4 + 3] = v.w;
    }
    __syncthreads();

    const int r = t >> 4;
    const int q = t & 15;
    const int row = n0 + r;
    const int sw = (row >> 1) & 3;
    float nsum = 0.f;
#pragma unroll
    for (int h = 0; h < 2; ++h) {
        const int j = q + (h << 4);
        const int ck = j >> 2;
        const int sq = (j & 3) ^ sw;
        const int c0 = j << 3;
        uint pk[4];
#pragma unroll
        for (int jj = 0; jj < 4; ++jj) {
            const float f0 = tile[c0 + 2 * jj][r];
            const float f1 = tile[c0 + 2 * jj + 1][r];
            const __hip_bfloat16 h0 = __float2bfloat16(f0);
            const __hip_bfloat16 h1 = __float2bfloat16(f1);
            const float q0 = __bfloat162float(h0), q1 = __bfloat162float(h1);
            nsum = fmaf(q0, q0, nsum);
            nsum = fmaf(q1, q1, nsum);
            pk[jj] = (uint)(*(const ushort*)&h0) | ((uint)(*(const ushort*)&h1) << 16);
        }
        *(uint4*)(Zc + (size_t)ck * CKS + (size_t)row * 32 + (sq << 3)) =
            make_uint4(pk[0], pk[1], pk[2], pk[3]);
    }
#pragma unroll
    for (int off = 1; off < 16; off <<= 1) nsum += __shfl_xor(nsum, off, 64);
    if (q == 0) norms[row] = nsum;
}

// ---- barrier-free GEMM: one 64x64 tile per wave, frags loaded direct from Zc ----
__global__ __launch_bounds__(256, 3) void gemm_epi(const ushort* __restrict__ Zc,
                                                   const float* __restrict__ norms,
                                                   const float* __restrict__ sigmas,
                                                   double* __restrict__ acc) {
    __shared__ float wsum[4];

    const int t = threadIdx.x;
    const int w = t >> 6, l = t & 63;
    const int L = (blockIdx.x << 2) + w;          // wave-tile id, 0..8255

#define TRI64(b) (((b) * (257 - (b))) / 2)
    int ti = (int)((257.0f - sqrtf(66049.0f - 8.0f * (float)L)) * 0.5f);
    ti = ti < 0 ? 0 : (ti > NT64 - 1 ? NT64 - 1 : ti);
    while (TRI64(ti + 1) <= L) ++ti;
    while (TRI64(ti) > L) --ti;
    const int tj = ti + (L - TRI64(ti));

    const int i0 = ti << 6, j0 = tj << 6;
    const int m = l & 15, q = l >> 4;

    // fragment addresses within chunk 0 (ushort units); chunk ck adds ck*CKS.
    // lane (m,q) -> row's stored quad q^((row>>1)&3): bijection onto the
    // contiguous 1KB block [ (i0+f*16)*64B , +1KB ) -> fully coalesced dwordx4.
    int offA[4], offB[4];
#pragma unroll
    for (int f = 0; f < 4; ++f) {
        const int ra = i0 + (f << 4) + m;
        offA[f] = (ra << 5) + (((q ^ ((ra >> 1) & 3))) << 3);
        const int rb = j0 + (f << 4) + m;
        offB[f] = (rb << 5) + (((q ^ ((rb >> 1) & 3))) << 3);
    }

    floatx4 accf[4][4];
#pragma unroll
    for (int fi = 0; fi < 4; ++fi)
#pragma unroll
        for (int fj = 0; fj < 4; ++fj) accf[fi][fj] = (floatx4){0.f, 0.f, 0.f, 0.f};

    short8 curA[4], curB[4], nxtA[4], nxtB[4];
#pragma unroll
    for (int f = 0; f < 4; ++f) {
        curA[f] = *(const short8*)(Zc + offA[f]);
        curB[f] = *(const short8*)(Zc + offB[f]);
    }

#pragma unroll
    for (int ck = 0; ck < 8; ++ck) {
        if (ck < 7) {
            const size_t ko = (size_t)(ck + 1) * CKS;
#pragma unroll
            for (int f = 0; f < 4; ++f) {
                nxtA[f] = *(const short8*)(Zc + ko + offA[f]);
                nxtB[f] = *(const short8*)(Zc + ko + offB[f]);
            }
        }
#pragma unroll
        for (int fi = 0; fi < 4; ++fi)
#pragma unroll
            for (int fj = 0; fj < 4; ++fj)
                accf[fi][fj] = __builtin_amdgcn_mfma_f32_16x16x32_bf16(curA[fi], curB[fj], accf[fi][fj], 0, 0, 0);
        if (ck < 7) {
#pragma unroll
            for (int f = 0; f < 4; ++f) { curA[f] = nxtA[f]; curB[f] = nxtB[f]; }
        }
    }

    // ---- epilogue (same as R6/R7, verified absmax 0) ----
    float c2[NSIG];
#pragma unroll
    for (int k = 0; k < NSIG; ++k) c2[k] = (-0.5f / sigmas[k]) * 1.44269504f;  // -beta*log2(e)

    const bool diag = (ti == tj);
    const float sgn2 = ((ti < 64) == (tj < 64)) ? 2.f : -2.f;

#pragma unroll
    for (int fi = 0; fi < 4; ++fi) {
        const floatx4 ni4 = *(const floatx4*)(norms + i0 + (fi << 4) + (q << 2));
#pragma unroll
        for (int fj = 0; fj < 4; ++fj) {
            const float njs = norms[j0 + (fj << 4) + m];
#pragma unroll
            for (int v = 0; v < 4; ++v) {
                float d = fmaf(-2.f, accf[fi][fj][v], ni4[v] + njs);
                d = fmaxf(d, 0.f);
                if (diag) {
                    const int dif = ((fi - fj) << 4) + ((q << 2) + v) - m;   // gi - gj
                    d = (dif < 0) ? d : 3.0e9f;   // keep strictly-upper pairs only
                }
                accf[fi][fj][v] = d;
            }
        }
    }

    float dmin = accf[0][0][0];
#pragma unroll
    for (int fi = 0; fi < 4; ++fi)
#pragma unroll
        for (int fj = 0; fj < 4; ++fj)
#pragma unroll
            for (int v = 0; v < 4; ++v) dmin = fminf(dmin, accf[fi][fj][v]);
#pragma unroll
    for (int off = 1; off < 64; off <<= 1) dmin = fminf(dmin, __shfl_xor(dmin, off, 64));

    float lsum = 0.f;
#pragma unroll
    for (int k = 0; k < NSIG; ++k) {
        if (c2[k] * dmin >= -126.f) {     // wave-uniform: skip iff every exp underflows (exact in fp32)
#pragma unroll
            for (int fi = 0; fi < 4; ++fi)
#pragma unroll
                for (int fj = 0; fj < 4; ++fj)
#pragma unroll
                    for (int v = 0; v < 4; ++v)
                        lsum += __builtin_amdgcn_exp2f(c2[k] * accf[fi][fj][v]);
        }
    }
    lsum *= sgn2;

#pragma unroll
    for (int off = 32; off > 0; off >>= 1) lsum += __shfl_down(lsum, off, 64);
    if (l == 0) wsum[w] = lsum;
    __syncthreads();
    if (t == 0) atomicAdd(acc, (double)(wsum[0] + wsum[1] + wsum[2] + wsum[3]));
}

__global__ void finalize_kernel(const double* __restrict__ acc, float* __restrict__ out) {
    out[0] = (float)((*acc + 8192.0 * NSIG) * (1.0 / (4096.0 * 4096.0)));
}

extern "C" void kernel_launch(void* const* d_in, const int* in_sizes, int n_in,
                              void* d_out, int out_size, void* d_ws, size_t ws_size,
                              hipStream_t stream) {
    const float* x   = (const float*)d_in[0];
    const float* y   = (const float*)d_in[1];
    const float* sig = (const float*)d_in[2];

    ushort* Zc   = (ushort*)d_ws;                                   // 4 MiB
    float* norms = (float*)((char*)d_ws + (size_t)8192 * 256 * 2);  // 32 KiB
    double* acc  = (double*)((char*)norms + 8192 * sizeof(float));
    float* out   = (float*)d_out;

    prep_kernel<<<512, 256, 0, stream>>>(x, y, Zc, norms, acc);
    gemm_epi<<<NBLK, 256, 0, stream>>>(Zc, norms, sig, acc);
    finalize_kernel<<<1, 1, 0, stream>>>(acc, out);
}

// Round 9
// 105.102 us; speedup vs baseline: 1.4286x; 1.0467x over previous
//
#include <hip/hip_runtime.h>
#include <hip/hip_bf16.h>

// MMD loss via bf16 MFMA Gram matrix — barrier-free LDS-free GEMM (R8 core),
// now with: 2x2 wave-tile blocks (L1 fragment sharing), panel-ordered block
// decode (L2 working-set = 512KB hot B-panel), and per-block partial stores
// (no single-address fp64 atomic serialization).
//
// Zc layout (R7): Zc[ck][row][32], stored quad = q ^ ((row>>1)&3); each mfma
// fragment = one contiguous coalesced 1KB block.
// Lessons: R4 no __threadfence in hot kernel; R5 no forced occupancy (spill);
// R6 no scattered vector loads; R3/R7 barrier-drain plateau.
//
// z = [xf; yf] (8192 x 256). result = (1/4096^2)*(8192*NSIG + sum_{i<j} 2 s_i s_j K_ij)
// ws: [0,4MiB) bf16 Zc; float norms[8192]; float partials[2080].

#define NSIG 5
#define CKS   262144                 // chunk stride in ushorts: 8192 rows * 32
#define NBLK2 2080                   // 64-supergrid triangle: 64*65/2

typedef __attribute__((ext_vector_type(8))) short short8;
typedef __attribute__((ext_vector_type(4))) float floatx4;

// ---- prep: (B,C,H,W) fp32 -> Zc chunked-swizzled bf16 + norms (unchanged) ----
__global__ __launch_bounds__(256) void prep_kernel(const float* __restrict__ x,
                                                   const float* __restrict__ y,
                                                   ushort* __restrict__ Zc,
                                                   float* __restrict__ norms) {
    const int bid = blockIdx.x;           // s(1) | b(2) | strip(6)
    const int t = threadIdx.x;
    const int s = bid >> 8;
    const int b = (bid >> 6) & 3;
    const int p0 = (bid & 63) << 4;
    const float* src = s ? y : x;
    const int n0 = (s << 12) + (b << 10) + p0;

    __shared__ float tile[256][17];

    const int cg = t >> 2;
    const int p4 = (t & 3) << 2;
#pragma unroll
    for (int pass = 0; pass < 4; ++pass) {
        const int c = cg + (pass << 6);
        const float4 v = *(const float4*)(src + (((size_t)((b << 8) + c)) << 10) + p0 + p4);
        tile[c][p4] = v.x; tile[c][p4 + 1] = v.y; tile[c][p4 + 2] = v.z; tile[c][p4 + 3] = v.w;
    }
    __syncthreads();

    const int r = t >> 4;
    const int q = t & 15;
    const int row = n0 + r;
    const int sw = (row >> 1) & 3;
    float nsum = 0.f;
#pragma unroll
    for (int h = 0; h < 2; ++h) {
        const int j = q + (h << 4);
        const int ck = j >> 2;
        const int sq = (j & 3) ^ sw;
        const int c0 = j << 3;
        uint pk[4];
#pragma unroll
        for (int jj = 0; jj < 4; ++jj) {
            const float f0 = tile[c0 + 2 * jj][r];
            const float f1 = tile[c0 + 2 * jj + 1][r];
            const __hip_bfloat16 h0 = __float2bfloat16(f0);
            const __hip_bfloat16 h1 = __float2bfloat16(f1);
            const float q0 = __bfloat162float(h0), q1 = __bfloat162float(h1);
            nsum = fmaf(q0, q0, nsum);
            nsum = fmaf(q1, q1, nsum);
            pk[jj] = (uint)(*(const ushort*)&h0) | ((uint)(*(const ushort*)&h1) << 16);
        }
        *(uint4*)(Zc + (size_t)ck * CKS + (size_t)row * 32 + (sq << 3)) =
            make_uint4(pk[0], pk[1], pk[2], pk[3]);
    }
#pragma unroll
    for (int off = 1; off < 16; off <<= 1) nsum += __shfl_xor(nsum, off, 32);
    if (q == 0) norms[row] = nsum;
}

// ---- GEMM: block = 2x2 wave-tiles (128x128), panel-ordered triangle decode ----
__global__ __launch_bounds__(256, 3) void gemm_epi(const ushort* __restrict__ Zc,
                                                   const float* __restrict__ norms,
                                                   const float* __restrict__ sigmas,
                                                   float* __restrict__ partials) {
    __shared__ float wsum[4];

    const int t = threadIdx.x;
    const int w = t >> 6, l = t & 63;

    // panel decode: panels p of 8 super-columns; P(p) = 32p^2 + 4p blocks before
    // panel p; within panel, column-major (column tj2 has tj2+1 blocks).
    const int lin = blockIdx.x;
    int p = (int)((-4.0f + sqrtf(16.0f + 128.0f * (float)lin)) * (1.0f / 64.0f));
    p = p < 0 ? 0 : (p > 7 ? 7 : p);
    while (p < 7 && 32 * (p + 1) * (p + 1) + 4 * (p + 1) <= lin) ++p;
    while (p > 0 && 32 * p * p + 4 * p > lin) --p;
    const int o = lin - (32 * p * p + 4 * p);
    int c = 7;
#pragma unroll
    for (int cc = 7; cc >= 1; --cc) {
        const int Q = cc * (8 * p + 1) + (cc * (cc - 1)) / 2;
        if (o < Q) c = cc - 1;
    }
    const int Qc = c * (8 * p + 1) + (c * (c - 1)) / 2;
    const int tj2 = 8 * p + c;
    const int ti2 = o - Qc;              // 0..tj2

    // wave -> 64x64 tile: ti = 2*ti2 + (w>>1), tj = 2*tj2 + (w&1)
    const int ti = (ti2 << 1) + (w >> 1);
    const int tj = (tj2 << 1) + (w & 1);
    const bool active = (ti <= tj);      // one lower-tri wave per diagonal block idles
    const bool diag = (ti == tj);

    const int i0 = ti << 6, j0 = tj << 6;
    const int m = l & 15, q = l >> 4;

    int offA[4], offB[4];
#pragma unroll
    for (int f = 0; f < 4; ++f) {
        const int ra = i0 + (f << 4) + m;
        offA[f] = (ra << 5) + (((q ^ ((ra >> 1) & 3))) << 3);
        const int rb = j0 + (f << 4) + m;
        offB[f] = (rb << 5) + (((q ^ ((rb >> 1) & 3))) << 3);
    }

    floatx4 accf[4][4];
#pragma unroll
    for (int fi = 0; fi < 4; ++fi)
#pragma unroll
        for (int fj = 0; fj < 4; ++fj) accf[fi][fj] = (floatx4){0.f, 0.f, 0.f, 0.f};

    float lsum = 0.f;
    if (active) {
        short8 curA[4], curB[4], nxtA[4], nxtB[4];
#pragma unroll
        for (int f = 0; f < 4; ++f) {
            curA[f] = *(const short8*)(Zc + offA[f]);
            curB[f] = *(const short8*)(Zc + offB[f]);
        }
#pragma unroll
        for (int ck = 0; ck < 8; ++ck) {
            if (ck < 7) {
                const size_t ko = (size_t)(ck + 1) * CKS;
#pragma unroll
                for (int f = 0; f < 4; ++f) {
                    nxtA[f] = *(const short8*)(Zc + ko + offA[f]);
                    nxtB[f] = *(const short8*)(Zc + ko + offB[f]);
                }
            }
#pragma unroll
            for (int fi = 0; fi < 4; ++fi)
#pragma unroll
                for (int fj = 0; fj < 4; ++fj)
                    accf[fi][fj] = __builtin_amdgcn_mfma_f32_16x16x32_bf16(curA[fi], curB[fj], accf[fi][fj], 0, 0, 0);
            if (ck < 7) {
#pragma unroll
                for (int f = 0; f < 4; ++f) { curA[f] = nxtA[f]; curB[f] = nxtB[f]; }
            }
        }

        // ---- epilogue ----
        float c2[NSIG];
#pragma unroll
        for (int k = 0; k < NSIG; ++k) c2[k] = (-0.5f / sigmas[k]) * 1.44269504f;

        const float sgn2 = ((ti < 64) == (tj < 64)) ? 2.f : -2.f;

#pragma unroll
        for (int fi = 0; fi < 4; ++fi) {
            const floatx4 ni4 = *(const floatx4*)(norms + i0 + (fi << 4) + (q << 2));
#pragma unroll
            for (int fj = 0; fj < 4; ++fj) {
                const float njs = norms[j0 + (fj << 4) + m];
#pragma unroll
                for (int v = 0; v < 4; ++v) {
                    float d = fmaf(-2.f, accf[fi][fj][v], ni4[v] + njs);
                    d = fmaxf(d, 0.f);
                    if (diag) {
                        const int dif = ((fi - fj) << 4) + ((q << 2) + v) - m;   // gi - gj
                        d = (dif < 0) ? d : 3.0e9f;    // strictly-upper only
                    }
                    accf[fi][fj][v] = d;
                }
            }
        }

        float dmin = accf[0][0][0];
#pragma unroll
        for (int fi = 0; fi < 4; ++fi)
#pragma unroll
            for (int fj = 0; fj < 4; ++fj)
#pragma unroll
                for (int v = 0; v < 4; ++v) dmin = fminf(dmin, accf[fi][fj][v]);
#pragma unroll
        for (int off = 1; off < 64; off <<= 1) dmin = fminf(dmin, __shfl_xor(dmin, off, 64));

#pragma unroll
        for (int k = 0; k < NSIG; ++k) {
            if (c2[k] * dmin >= -126.f) {   // wave-uniform skip iff all exps underflow (exact in fp32)
#pragma unroll
                for (int fi = 0; fi < 4; ++fi)
#pragma unroll
                    for (int fj = 0; fj < 4; ++fj)
#pragma unroll
                        for (int v = 0; v < 4; ++v)
                            lsum += __builtin_amdgcn_exp2f(c2[k] * accf[fi][fj][v]);
            }
        }
        lsum *= sgn2;
    }

#pragma unroll
    for (int off = 32; off > 0; off >>= 1) lsum += __shfl_down(lsum, off, 64);
    if (l == 0) wsum[w] = lsum;
    __syncthreads();
    if (t == 0) partials[blockIdx.x] = wsum[0] + wsum[1] + wsum[2] + wsum[3];
}

__global__ __launch_bounds__(256) void finalize_kernel(const float* __restrict__ partials,
                                                       float* __restrict__ out) {
    __shared__ double sh[256];
    const int t = threadIdx.x;
    double s = 0.0;
    for (int i = t; i < NBLK2; i += 256) s += (double)partials[i];
    sh[t] = s;
    __syncthreads();
    for (int st = 128; st > 0; st >>= 1) {
        if (t < st) sh[t] += sh[t + st];
        __syncthreads();
    }
    if (t == 0) out[0] = (float)((sh[0] + 8192.0 * NSIG) * (1.0 / (4096.0 * 4096.0)));
}

extern "C" void kernel_launch(void* const* d_in, const int* in_sizes, int n_in,
                              void* d_out, int out_size, void* d_ws, size_t ws_size,
                              hipStream_t stream) {
    const float* x   = (const float*)d_in[0];
    const float* y   = (const float*)d_in[1];
    const float* sig = (const float*)d_in[2];

    ushort* Zc      = (ushort*)d_ws;                                   // 4 MiB
    float* norms    = (float*)((char*)d_ws + (size_t)8192 * 256 * 2);  // 32 KiB
    float* partials = (float*)((char*)norms + 8192 * sizeof(float));   // 2080 floats
    float* out      = (float*)d_out;

    prep_kernel<<<512, 256, 0, stream>>>(x, y, Zc, norms);
    gemm_epi<<<NBLK2, 256, 0, stream>>>(Zc, norms, sig, partials);
    finalize_kernel<<<1, 256, 0, stream>>>(partials, out);
}